// Round 2
// baseline (606.293 us; speedup 1.0000x reference)
//
#include <hip/hip_runtime.h>
#include <hip/hip_bf16.h>

// GraphAutoencoder: 2x GCNConv (128->128->64) + 2x Linear decoder (64->128->128)
// N=50000, E=600000. Round 2: dtype-sniffing build — a device-side probe
// determines at runtime whether float tensors arrived as fp32 or bf16, and
// whether edge_index arrived as int64 or int32. All compute kernels branch
// (wave-uniformly) on the sniffed flags. Intermediates are fp32 in ws.

#define N_FEAT 128
#define HID    128
#define OUTD   64

// flag-dependent external load (weights / x / biases)
__device__ __forceinline__ float ldx(const void* p, size_t i, int f32) {
    return f32 ? ((const float*)p)[i]
               : __bfloat162float(((const __hip_bfloat16*)p)[i]);
}

// ---------------- dtype sniffer ----------------
// flags[0] = 1 if float tensors are fp32 (else bf16)
// flags[1] = 1 if edge_index is int64 (else int32)
__global__ void k_sniff(const void* __restrict__ x, const void* __restrict__ ei,
                        int* __restrict__ flags) {
    __shared__ int cnt[2];
    int t = threadIdx.x;
    if (t < 2) cnt[t] = 0;
    __syncthreads();
    // bf16 interpretation of x: garbage values => data is fp32
    const __hip_bfloat16* xb = (const __hip_bfloat16*)x;
    int local = 0;
    for (int i = t; i < 4096; i += 256) {
        float v = __bfloat162float(xb[i]);
        if (!(fabsf(v) < 1e4f)) local++;   // also catches NaN/Inf
    }
    if (local) atomicAdd(&cnt[0], local);
    // int32 interpretation of edge_index: odd words all zero => data is int64
    const int* e32 = (const int*)ei;
    if (t < 128 && e32[2 * t + 1] == 0) atomicAdd(&cnt[1], 1);
    __syncthreads();
    if (t == 0) {
        flags[0] = (cnt[0] > 8) ? 1 : 0;
        flags[1] = (cnt[1] > 100) ? 1 : 0;
    }
}

// ---------------- CSR build ----------------

__device__ __forceinline__ int ld_edge(const void* ei, size_t i, int i64) {
    return i64 ? (int)((const long long*)ei)[i] : ((const int*)ei)[i];
}

__global__ void k_deg(const void* __restrict__ ei, int E, int* __restrict__ deg,
                      int n, const int* __restrict__ flags) {
    int e = blockIdx.x * blockDim.x + threadIdx.x;
    if (e >= E) return;
    int c = ld_edge(ei, (size_t)E + e, flags[1]);   // col = target
    if ((unsigned)c < (unsigned)n) atomicAdd(&deg[c], 1);
}

// One block, 1024 threads: exclusive scan of deg -> csr_ptr, cursor; dis = rsqrt(deg+1)
__global__ void k_scan_dis(const int* __restrict__ deg, int* __restrict__ csr_ptr,
                           int* __restrict__ cursor, float* __restrict__ dis, int n) {
    __shared__ int sums[1024];
    int t = threadIdx.x;
    const int CH = (n + 1023) / 1024;
    int beg = t * CH;
    int end = beg + CH; if (end > n) end = n;
    int s = 0;
    for (int i = beg; i < end; ++i) s += deg[i];
    sums[t] = s;
    __syncthreads();
    for (int off = 1; off < 1024; off <<= 1) {
        int v = (t >= off) ? sums[t - off] : 0;
        __syncthreads();
        sums[t] += v;
        __syncthreads();
    }
    int run = (t == 0) ? 0 : sums[t - 1];
    for (int i = beg; i < end; ++i) {
        int d = deg[i];
        csr_ptr[i] = run;
        cursor[i] = run;
        dis[i] = rsqrtf((float)(d + 1));   // +1 self-loop
        run += d;
    }
    if (t == 1023) csr_ptr[n] = run;
}

__global__ void k_fill(const void* __restrict__ ei, int E, int* __restrict__ cursor,
                       int* __restrict__ csr_src, int n, const int* __restrict__ flags) {
    int e = blockIdx.x * blockDim.x + threadIdx.x;
    if (e >= E) return;
    int i64 = flags[1];
    int r = ld_edge(ei, (size_t)e, i64);            // row = source
    int c = ld_edge(ei, (size_t)E + e, i64);        // col = target
    if ((unsigned)c >= (unsigned)n || (unsigned)r >= (unsigned)n) return;
    int pos = atomicAdd(&cursor[c], 1);
    csr_src[pos] = r;
}

// ---------------- GEMM: C[M,N] = A[M,K] @ B[K,N] (+bias)(+relu) ----------------
// BM=BN=64, BK=32, 256 threads, 4x4 per thread, fp32 accumulate.
// a_ext: A is an external tensor (dtype per flag); else fp32 workspace.
// c_ext: C is the external output (dtype per flag); else fp32 workspace.

__global__ void k_gemm(const void* __restrict__ A, int a_ext,
                       const void* __restrict__ B, const void* __restrict__ bias,
                       void* __restrict__ C, int c_ext,
                       int M, int K, int N, int relu, const int* __restrict__ flags) {
    __shared__ float As[32][68];   // [k][m]
    __shared__ float Bs[32][68];   // [k][n]
    const int f32 = flags[0];
    int t = threadIdx.x;
    int m0 = blockIdx.x * 64, n0 = blockIdx.y * 64;
    int tm = (t >> 4) << 2;
    int tn = (t & 15) << 2;
    float acc[4][4] = {};

    for (int k0 = 0; k0 < K; k0 += 32) {
#pragma unroll
        for (int i = 0; i < 8; ++i) {      // A tile 64x32
            int idx = t + i * 256;
            int r = idx >> 5, c = idx & 31;
            int m = m0 + r;
            float v = 0.f;
            if (m < M) {
                size_t off = (size_t)m * K + k0 + c;
                v = a_ext ? ldx(A, off, f32) : ((const float*)A)[off];
            }
            As[c][r] = v;
        }
#pragma unroll
        for (int i = 0; i < 8; ++i) {      // B tile 32x64
            int idx = t + i * 256;
            int r = idx >> 6, c = idx & 63;
            Bs[r][c] = ldx(B, (size_t)(k0 + r) * N + n0 + c, f32);
        }
        __syncthreads();
#pragma unroll
        for (int k = 0; k < 32; ++k) {
            float4 a4 = *(const float4*)&As[k][tm];
            float4 b4 = *(const float4*)&Bs[k][tn];
            float av[4] = {a4.x, a4.y, a4.z, a4.w};
            float bv[4] = {b4.x, b4.y, b4.z, b4.w};
#pragma unroll
            for (int i = 0; i < 4; ++i)
#pragma unroll
                for (int j = 0; j < 4; ++j) acc[i][j] += av[i] * bv[j];
        }
        __syncthreads();
    }

    float bv[4] = {0.f, 0.f, 0.f, 0.f};
    if (bias) {
#pragma unroll
        for (int j = 0; j < 4; ++j) bv[j] = ldx(bias, n0 + tn + j, f32);
    }
#pragma unroll
    for (int i = 0; i < 4; ++i) {
        int m = m0 + tm + i;
        if (m >= M) continue;
#pragma unroll
        for (int j = 0; j < 4; ++j) {
            float v = acc[i][j] + bv[j];
            if (relu) v = fmaxf(v, 0.f);
            size_t off = (size_t)m * N + n0 + tn + j;
            if (c_ext) {
                if (f32) ((float*)C)[off] = v;
                else     ((__hip_bfloat16*)C)[off] = __float2bfloat16(v);
            } else {
                ((float*)C)[off] = v;
            }
        }
    }
}

// ---------------- CSR aggregation (one wave per node) + bias + relu ----------------

template <int F>
__global__ void k_agg(const float* __restrict__ xw, const int* __restrict__ csr_ptr,
                      const int* __restrict__ csr_src, const float* __restrict__ dis,
                      const void* __restrict__ bias, float* __restrict__ out,
                      int n_nodes, const int* __restrict__ flags) {
    int gw = (int)((blockIdx.x * (size_t)blockDim.x + threadIdx.x) >> 6);
    int lane = threadIdx.x & 63;
    if (gw >= n_nodes) return;
    const int f32 = flags[0];
    int n = gw;
    int beg = csr_ptr[n], end = csr_ptr[n + 1];
    float dn = dis[n];
    if (F == 128) {
        const float2* xw2 = (const float2*)xw;
        float2 acc = {0.f, 0.f};
        for (int j = beg; j < end; ++j) {
            int s = csr_src[j];
            float w = dis[s] * dn;
            float2 v = xw2[(size_t)s * 64 + lane];
            acc.x += v.x * w;
            acc.y += v.y * w;
        }
        float2 vs = xw2[(size_t)n * 64 + lane];
        float wl = dn * dn;
        acc.x += vs.x * wl;
        acc.y += vs.y * wl;
        acc.x = fmaxf(acc.x + ldx(bias, lane * 2, f32), 0.f);
        acc.y = fmaxf(acc.y + ldx(bias, lane * 2 + 1, f32), 0.f);
        ((float2*)out)[(size_t)n * 64 + lane] = acc;
    } else {  // F == 64
        float acc = 0.f;
        for (int j = beg; j < end; ++j) {
            int s = csr_src[j];
            acc += xw[(size_t)s * 64 + lane] * (dis[s] * dn);
        }
        acc += xw[(size_t)n * 64 + lane] * dn * dn;
        acc = fmaxf(acc + ldx(bias, lane, f32), 0.f);
        out[(size_t)n * 64 + lane] = acc;
    }
}

// ---------------- launch ----------------

extern "C" void kernel_launch(void* const* d_in, const int* in_sizes, int n_in,
                              void* d_out, int out_size, void* d_ws, size_t ws_size,
                              hipStream_t stream) {
    const void* x   = d_in[0];
    const void* ei  = d_in[1];
    const void* W1  = d_in[2];
    const void* b1  = d_in[3];
    const void* W2  = d_in[4];
    const void* b2  = d_in[5];
    const void* Wd1 = d_in[6];
    const void* bd1 = d_in[7];
    const void* Wd2 = d_in[8];
    const void* bd2 = d_in[9];

    const int n = in_sizes[0] / N_FEAT;    // 50000
    const int E = in_sizes[1] / 2;         // 600000

    // workspace carve (fp32 intermediates, tight aliasing ~54.4 MB)
    float* bufA   = (float*)d_ws;                  // [n,128]  xw1 / xw2 / h3
    float* bufB   = bufA + (size_t)n * 128;        // [n,128]  h1 / h2
    float* dis    = bufB + (size_t)n * 128;        // [n]
    int*   flags  = (int*)(dis + n);               // [2]
    int*   deg    = flags + 2;                     // [n]
    int*   csr_ptr= deg + n;                       // [n+1]
    int*   cursor = csr_ptr + (n + 1);             // [n]
    int*   csr_src= cursor + n;                    // [E]

    k_sniff<<<1, 256, 0, stream>>>(x, ei, flags);

    // --- CSR build ---
    hipMemsetAsync(deg, 0, (size_t)n * sizeof(int), stream);
    {
        int blk = 256, grd = (E + blk - 1) / blk;
        k_deg<<<grd, blk, 0, stream>>>(ei, E, deg, n, flags);
        k_scan_dis<<<1, 1024, 0, stream>>>(deg, csr_ptr, cursor, dis, n);
        k_fill<<<grd, blk, 0, stream>>>(ei, E, cursor, csr_src, n, flags);
    }

    dim3 blk(256);
    int mg = (n + 63) / 64;

    // layer 1: bufA = x @ W1 ; bufB = relu(agg(bufA) + b1)
    k_gemm<<<dim3(mg, HID / 64), blk, 0, stream>>>(
        x, 1, W1, nullptr, bufA, 0, n, N_FEAT, HID, 0, flags);
    k_agg<HID><<<(n * 64 + 255) / 256, 256, 0, stream>>>(
        bufA, csr_ptr, csr_src, dis, b1, bufB, n, flags);

    // layer 2: bufA = bufB @ W2 ; bufB = relu(agg(bufA) + b2)
    k_gemm<<<dim3(mg, OUTD / 64), blk, 0, stream>>>(
        bufB, 0, W2, nullptr, bufA, 0, n, HID, OUTD, 0, flags);
    k_agg<OUTD><<<(n + 3) / 4, 256, 0, stream>>>(
        bufA, csr_ptr, csr_src, dis, b2, bufB, n, flags);

    // decoder: bufA = relu(bufB @ Wd1 + bd1) ; out = bufA @ Wd2 + bd2
    k_gemm<<<dim3(mg, HID / 64), blk, 0, stream>>>(
        bufB, 0, Wd1, bd1, bufA, 0, n, OUTD, HID, 1, flags);
    k_gemm<<<dim3(mg, N_FEAT / 64), blk, 0, stream>>>(
        bufA, 0, Wd2, bd2, d_out, 1, n, HID, N_FEAT, 0, flags);
}

// Round 3
// 474.732 us; speedup vs baseline: 1.2771x; 1.2771x over previous
//
#include <hip/hip_runtime.h>
#include <hip/hip_bf16.h>

// GraphAutoencoder: 2x GCNConv (128->128->64) + 2x Linear decoder (64->128->128)
// N=50000, E=600000. Round 3: replace the single-block scan (134 us, 22% of
// runtime, latency-bound on 1 CU) with a 3-phase hierarchical scan (~5 us).
// Everything else unchanged from the passing round-2 build.

#define N_FEAT 128
#define HID    128
#define OUTD   64

__device__ __forceinline__ float ldx(const void* p, size_t i, int f32) {
    return f32 ? ((const float*)p)[i]
               : __bfloat162float(((const __hip_bfloat16*)p)[i]);
}

// ---------------- dtype sniffer ----------------
__global__ void k_sniff(const void* __restrict__ x, const void* __restrict__ ei,
                        int* __restrict__ flags) {
    __shared__ int cnt[2];
    int t = threadIdx.x;
    if (t < 2) cnt[t] = 0;
    __syncthreads();
    const __hip_bfloat16* xb = (const __hip_bfloat16*)x;
    int local = 0;
    for (int i = t; i < 4096; i += 256) {
        float v = __bfloat162float(xb[i]);
        if (!(fabsf(v) < 1e4f)) local++;
    }
    if (local) atomicAdd(&cnt[0], local);
    const int* e32 = (const int*)ei;
    if (t < 128 && e32[2 * t + 1] == 0) atomicAdd(&cnt[1], 1);
    __syncthreads();
    if (t == 0) {
        flags[0] = (cnt[0] > 8) ? 1 : 0;
        flags[1] = (cnt[1] > 100) ? 1 : 0;
    }
}

// ---------------- CSR build ----------------

__device__ __forceinline__ int ld_edge(const void* ei, size_t i, int i64) {
    return i64 ? (int)((const long long*)ei)[i] : ((const int*)ei)[i];
}

__global__ void k_deg(const void* __restrict__ ei, int E, int* __restrict__ deg,
                      int n, const int* __restrict__ flags) {
    int e = blockIdx.x * blockDim.x + threadIdx.x;
    if (e >= E) return;
    int c = ld_edge(ei, (size_t)E + e, flags[1]);
    if ((unsigned)c < (unsigned)n) atomicAdd(&deg[c], 1);
}

// Phase 1: per-block (1024-wide) exclusive scan; local prefix -> part, totals -> bsums
__global__ void k_scan1(const int* __restrict__ deg, int* __restrict__ part,
                        int* __restrict__ bsums, int n) {
    __shared__ int s[1024];
    int t = threadIdx.x;
    int i = blockIdx.x * 1024 + t;
    int v = (i < n) ? deg[i] : 0;
    s[t] = v;
    __syncthreads();
    for (int off = 1; off < 1024; off <<= 1) {
        int u = (t >= off) ? s[t - off] : 0;
        __syncthreads();
        s[t] += u;
        __syncthreads();
    }
    if (i < n) part[i] = s[t] - v;          // exclusive within block
    if (t == 1023) bsums[blockIdx.x] = s[t];
}

// Phase 2: one small block scans the <=64 block sums (exclusive, in place)
__global__ void k_scan2(int* __restrict__ bsums, int nb) {
    __shared__ int s[64];
    int t = threadIdx.x;
    int v = (t < nb) ? bsums[t] : 0;
    s[t] = v;
    __syncthreads();
    for (int off = 1; off < 64; off <<= 1) {
        int u = (t >= off) ? s[t - off] : 0;
        __syncthreads();
        s[t] += u;
        __syncthreads();
    }
    if (t < nb) bsums[t] = s[t] - v;
}

// Phase 3: apply block offsets; emit csr_ptr, cursor, dis
__global__ void k_scan3(const int* __restrict__ deg, const int* __restrict__ part,
                        const int* __restrict__ bsums, int* __restrict__ csr_ptr,
                        int* __restrict__ cursor, float* __restrict__ dis, int n) {
    int i = blockIdx.x * 1024 + threadIdx.x;
    if (i >= n) return;
    int d = deg[i];
    int p = part[i] + bsums[blockIdx.x];
    csr_ptr[i] = p;
    cursor[i] = p;
    dis[i] = rsqrtf((float)(d + 1));
    if (i == n - 1) csr_ptr[n] = p + d;     // grand total
}

__global__ void k_fill(const void* __restrict__ ei, int E, int* __restrict__ cursor,
                       int* __restrict__ csr_src, int n, const int* __restrict__ flags) {
    int e = blockIdx.x * blockDim.x + threadIdx.x;
    if (e >= E) return;
    int i64 = flags[1];
    int r = ld_edge(ei, (size_t)e, i64);
    int c = ld_edge(ei, (size_t)E + e, i64);
    if ((unsigned)c >= (unsigned)n || (unsigned)r >= (unsigned)n) return;
    int pos = atomicAdd(&cursor[c], 1);
    csr_src[pos] = r;
}

// ---------------- GEMM: C[M,N] = A[M,K] @ B[K,N] (+bias)(+relu) ----------------

__global__ void k_gemm(const void* __restrict__ A, int a_ext,
                       const void* __restrict__ B, const void* __restrict__ bias,
                       void* __restrict__ C, int c_ext,
                       int M, int K, int N, int relu, const int* __restrict__ flags) {
    __shared__ float As[32][68];
    __shared__ float Bs[32][68];
    const int f32 = flags[0];
    int t = threadIdx.x;
    int m0 = blockIdx.x * 64, n0 = blockIdx.y * 64;
    int tm = (t >> 4) << 2;
    int tn = (t & 15) << 2;
    float acc[4][4] = {};

    for (int k0 = 0; k0 < K; k0 += 32) {
#pragma unroll
        for (int i = 0; i < 8; ++i) {
            int idx = t + i * 256;
            int r = idx >> 5, c = idx & 31;
            int m = m0 + r;
            float v = 0.f;
            if (m < M) {
                size_t off = (size_t)m * K + k0 + c;
                v = a_ext ? ldx(A, off, f32) : ((const float*)A)[off];
            }
            As[c][r] = v;
        }
#pragma unroll
        for (int i = 0; i < 8; ++i) {
            int idx = t + i * 256;
            int r = idx >> 6, c = idx & 63;
            Bs[r][c] = ldx(B, (size_t)(k0 + r) * N + n0 + c, f32);
        }
        __syncthreads();
#pragma unroll
        for (int k = 0; k < 32; ++k) {
            float4 a4 = *(const float4*)&As[k][tm];
            float4 b4 = *(const float4*)&Bs[k][tn];
            float av[4] = {a4.x, a4.y, a4.z, a4.w};
            float bv[4] = {b4.x, b4.y, b4.z, b4.w};
#pragma unroll
            for (int i = 0; i < 4; ++i)
#pragma unroll
                for (int j = 0; j < 4; ++j) acc[i][j] += av[i] * bv[j];
        }
        __syncthreads();
    }

    float bv[4] = {0.f, 0.f, 0.f, 0.f};
    if (bias) {
#pragma unroll
        for (int j = 0; j < 4; ++j) bv[j] = ldx(bias, n0 + tn + j, f32);
    }
#pragma unroll
    for (int i = 0; i < 4; ++i) {
        int m = m0 + tm + i;
        if (m >= M) continue;
#pragma unroll
        for (int j = 0; j < 4; ++j) {
            float v = acc[i][j] + bv[j];
            if (relu) v = fmaxf(v, 0.f);
            size_t off = (size_t)m * N + n0 + tn + j;
            if (c_ext) {
                if (f32) ((float*)C)[off] = v;
                else     ((__hip_bfloat16*)C)[off] = __float2bfloat16(v);
            } else {
                ((float*)C)[off] = v;
            }
        }
    }
}

// ---------------- CSR aggregation (one wave per node) + bias + relu ----------------

template <int F>
__global__ void k_agg(const float* __restrict__ xw, const int* __restrict__ csr_ptr,
                      const int* __restrict__ csr_src, const float* __restrict__ dis,
                      const void* __restrict__ bias, float* __restrict__ out,
                      int n_nodes, const int* __restrict__ flags) {
    int gw = (int)((blockIdx.x * (size_t)blockDim.x + threadIdx.x) >> 6);
    int lane = threadIdx.x & 63;
    if (gw >= n_nodes) return;
    const int f32 = flags[0];
    int n = gw;
    int beg = csr_ptr[n], end = csr_ptr[n + 1];
    float dn = dis[n];
    if (F == 128) {
        const float2* xw2 = (const float2*)xw;
        float2 acc = {0.f, 0.f};
        for (int j = beg; j < end; ++j) {
            int s = csr_src[j];
            float w = dis[s] * dn;
            float2 v = xw2[(size_t)s * 64 + lane];
            acc.x += v.x * w;
            acc.y += v.y * w;
        }
        float2 vs = xw2[(size_t)n * 64 + lane];
        float wl = dn * dn;
        acc.x += vs.x * wl;
        acc.y += vs.y * wl;
        acc.x = fmaxf(acc.x + ldx(bias, lane * 2, f32), 0.f);
        acc.y = fmaxf(acc.y + ldx(bias, lane * 2 + 1, f32), 0.f);
        ((float2*)out)[(size_t)n * 64 + lane] = acc;
    } else {  // F == 64
        float acc = 0.f;
        for (int j = beg; j < end; ++j) {
            int s = csr_src[j];
            acc += xw[(size_t)s * 64 + lane] * (dis[s] * dn);
        }
        acc += xw[(size_t)n * 64 + lane] * dn * dn;
        acc = fmaxf(acc + ldx(bias, lane, f32), 0.f);
        out[(size_t)n * 64 + lane] = acc;
    }
}

// ---------------- launch ----------------

extern "C" void kernel_launch(void* const* d_in, const int* in_sizes, int n_in,
                              void* d_out, int out_size, void* d_ws, size_t ws_size,
                              hipStream_t stream) {
    const void* x   = d_in[0];
    const void* ei  = d_in[1];
    const void* W1  = d_in[2];
    const void* b1  = d_in[3];
    const void* W2  = d_in[4];
    const void* b2  = d_in[5];
    const void* Wd1 = d_in[6];
    const void* bd1 = d_in[7];
    const void* Wd2 = d_in[8];
    const void* bd2 = d_in[9];

    const int n = in_sizes[0] / N_FEAT;    // 50000
    const int E = in_sizes[1] / 2;         // 600000

    float* bufA   = (float*)d_ws;                  // [n,128]
    float* bufB   = bufA + (size_t)n * 128;        // [n,128]
    float* dis    = bufB + (size_t)n * 128;        // [n]
    int*   flags  = (int*)(dis + n);               // [2]
    int*   deg    = flags + 2;                     // [n]
    int*   csr_ptr= deg + n;                       // [n+1]
    int*   cursor = csr_ptr + (n + 1);             // [n]
    int*   part   = cursor + n;                    // [n] scan temp
    int*   bsums  = part + n;                      // [64]
    int*   csr_src= bsums + 64;                    // [E]

    k_sniff<<<1, 256, 0, stream>>>(x, ei, flags);

    hipMemsetAsync(deg, 0, (size_t)n * sizeof(int), stream);
    {
        int blk = 256, grd = (E + blk - 1) / blk;
        int nb = (n + 1023) / 1024;                // 49
        k_deg<<<grd, blk, 0, stream>>>(ei, E, deg, n, flags);
        k_scan1<<<nb, 1024, 0, stream>>>(deg, part, bsums, n);
        k_scan2<<<1, 64, 0, stream>>>(bsums, nb);
        k_scan3<<<nb, 1024, 0, stream>>>(deg, part, bsums, csr_ptr, cursor, dis, n);
        k_fill<<<grd, blk, 0, stream>>>(ei, E, cursor, csr_src, n, flags);
    }

    dim3 blk(256);
    int mg = (n + 63) / 64;

    // layer 1
    k_gemm<<<dim3(mg, HID / 64), blk, 0, stream>>>(
        x, 1, W1, nullptr, bufA, 0, n, N_FEAT, HID, 0, flags);
    k_agg<HID><<<(n * 64 + 255) / 256, 256, 0, stream>>>(
        bufA, csr_ptr, csr_src, dis, b1, bufB, n, flags);

    // layer 2
    k_gemm<<<dim3(mg, OUTD / 64), blk, 0, stream>>>(
        bufB, 0, W2, nullptr, bufA, 0, n, HID, OUTD, 0, flags);
    k_agg<OUTD><<<(n + 3) / 4, 256, 0, stream>>>(
        bufA, csr_ptr, csr_src, dis, b2, bufB, n, flags);

    // decoder
    k_gemm<<<dim3(mg, HID / 64), blk, 0, stream>>>(
        bufB, 0, Wd1, bd1, bufA, 0, n, OUTD, HID, 1, flags);
    k_gemm<<<dim3(mg, N_FEAT / 64), blk, 0, stream>>>(
        bufA, 0, Wd2, bd2, d_out, 1, n, HID, N_FEAT, 0, flags);
}

// Round 6
// 346.573 us; speedup vs baseline: 1.7494x; 1.3698x over previous
//
#include <hip/hip_runtime.h>
#include <hip/hip_bf16.h>

// GraphAutoencoder: 2x GCNConv (128->128->64) + 2x Linear decoder (64->128->128)
// N=50000, E=600000. Round 6 — settled dtype convention (r1..r5 evidence):
//   floats arrive fp32, edge_index arrives int32, d_out is fp32.
// Plan: convert x & weights to bf16 once; bf16 activations; MFMA 16x16x32
// GEMMs (LDS-free, m97-style fragments); CSR gather aggregation in bf16;
// final GEMM writes fp32 to d_out. fp32 biases read directly.

#define N_FEAT 128
#define HID    128
#define OUTD   64

typedef __hip_bfloat16 bf16;
typedef __attribute__((ext_vector_type(8))) short short8;   // 8 bf16 = 4 VGPRs
typedef __attribute__((ext_vector_type(4))) float f32x4;    // MFMA accumulator

// ---------------- fp32 -> bf16 conversion (x) ----------------

__global__ void k_cvt(const float* __restrict__ src, bf16* __restrict__ dst, int count4) {
    int i = blockIdx.x * blockDim.x + threadIdx.x;
    if (i >= count4) return;
    float4 v = ((const float4*)src)[i];
    bf16 o[4] = {__float2bfloat16(v.x), __float2bfloat16(v.y),
                 __float2bfloat16(v.z), __float2bfloat16(v.w)};
    *(ushort2*)(dst + i * 4)     = *(ushort2*)&o[0];
    *(ushort2*)(dst + i * 4 + 2) = *(ushort2*)&o[2];
}

// ---------------- CSR build (edge_index int32) ----------------

__global__ void k_deg(const int* __restrict__ col, int E, int* __restrict__ deg,
                      int n) {
    int e = blockIdx.x * blockDim.x + threadIdx.x;
    if (e >= E) return;
    int c = col[e];
    if ((unsigned)c < (unsigned)n) atomicAdd(&deg[c], 1);
}

__global__ void k_scan1(const int* __restrict__ deg, int* __restrict__ part,
                        int* __restrict__ bsums, int n) {
    __shared__ int s[1024];
    int t = threadIdx.x;
    int i = blockIdx.x * 1024 + t;
    int v = (i < n) ? deg[i] : 0;
    s[t] = v;
    __syncthreads();
    for (int off = 1; off < 1024; off <<= 1) {
        int u = (t >= off) ? s[t - off] : 0;
        __syncthreads();
        s[t] += u;
        __syncthreads();
    }
    if (i < n) part[i] = s[t] - v;
    if (t == 1023) bsums[blockIdx.x] = s[t];
}

__global__ void k_scan2(int* __restrict__ bsums, int nb) {
    __shared__ int s[64];
    int t = threadIdx.x;
    int v = (t < nb) ? bsums[t] : 0;
    s[t] = v;
    __syncthreads();
    for (int off = 1; off < 64; off <<= 1) {
        int u = (t >= off) ? s[t - off] : 0;
        __syncthreads();
        s[t] += u;
        __syncthreads();
    }
    if (t < nb) bsums[t] = s[t] - v;
}

__global__ void k_scan3(const int* __restrict__ deg, const int* __restrict__ part,
                        const int* __restrict__ bsums, int* __restrict__ csr_ptr,
                        int* __restrict__ cursor, float* __restrict__ dis, int n) {
    int i = blockIdx.x * 1024 + threadIdx.x;
    if (i >= n) return;
    int d = deg[i];
    int p = part[i] + bsums[blockIdx.x];
    csr_ptr[i] = p;
    cursor[i] = p;
    dis[i] = rsqrtf((float)(d + 1));
    if (i == n - 1) csr_ptr[n] = p + d;
}

__global__ void k_fill(const int* __restrict__ row, const int* __restrict__ col,
                       int E, int* __restrict__ cursor,
                       int* __restrict__ csr_src, int n) {
    int e = blockIdx.x * blockDim.x + threadIdx.x;
    if (e >= E) return;
    int r = row[e];
    int c = col[e];
    if ((unsigned)c >= (unsigned)n || (unsigned)r >= (unsigned)n) return;
    int pos = atomicAdd(&cursor[c], 1);
    csr_src[pos] = r;
}

// ---------------- weight transpose + fp32->bf16: Wt[n*K+k] = bf16(W[k*N+n]) ----------------

__global__ void k_tr4(const float* __restrict__ Wa, bf16* __restrict__ Ta,
                      const float* __restrict__ Wb, bf16* __restrict__ Tb,
                      const float* __restrict__ Wc, bf16* __restrict__ Tc,
                      const float* __restrict__ Wd, bf16* __restrict__ Td) {
    int which = blockIdx.y;
    const float* W; bf16* T; int K, N;
    if (which == 0)      { W = Wa; T = Ta; K = 128; N = 128; }
    else if (which == 1) { W = Wb; T = Tb; K = 128; N = 64;  }
    else if (which == 2) { W = Wc; T = Tc; K = 64;  N = 128; }
    else                 { W = Wd; T = Td; K = 128; N = 128; }
    int i = blockIdx.x * 256 + threadIdx.x;
    if (i >= K * N) return;
    int k = i / N, nn = i - k * N;
    T[nn * K + k] = __float2bfloat16(W[i]);
}

// ---------------- MFMA GEMM: C[M,N] = A[M,K] @ Wt[N,K]^T (+bias)(+relu) ----------------
// LDS-free: block 256 = 4 waves; block tile 64x64; wave tile 32x32 (2x2 of 16x16).
// A-frag:  lane holds A[m=l16][k0 + quad*8 + j]   (m97-verified layout)
// B-frag:  lane holds Bt[n=l16][k0 + quad*8 + j]  (B^T treated as second A)
// D-layout: col = l16, row = quad*4 + r (m89-verified).
// bias fp32; out_f32 selects fp32 (d_out) vs bf16 (intermediate) store.

__global__ void k_gemm_mfma(const bf16* __restrict__ A, const bf16* __restrict__ Bt,
                            const float* __restrict__ bias, void* __restrict__ C,
                            int out_f32, int M, int K, int N, int relu) {
    int t = threadIdx.x;
    int lane = t & 63, w = t >> 6;
    int quad = lane >> 4, l16 = lane & 15;
    int m0 = blockIdx.x * 64 + (w & 1) * 32;
    int n0 = blockIdx.y * 64 + (w >> 1) * 32;
    int kq = quad * 8;

    short8 zero8 = {0, 0, 0, 0, 0, 0, 0, 0};
    f32x4 acc[2][2];
#pragma unroll
    for (int mi = 0; mi < 2; ++mi)
#pragma unroll
        for (int ni = 0; ni < 2; ++ni)
#pragma unroll
            for (int r = 0; r < 4; ++r) acc[mi][ni][r] = 0.f;

    int mrow[2];
    bool mok[2];
#pragma unroll
    for (int mi = 0; mi < 2; ++mi) {
        mrow[mi] = m0 + mi * 16 + l16;
        mok[mi] = mrow[mi] < M;
    }

    for (int k0 = 0; k0 < K; k0 += 32) {
        short8 af[2], bfm[2];
#pragma unroll
        for (int mi = 0; mi < 2; ++mi)
            af[mi] = mok[mi] ? *(const short8*)(A + (size_t)mrow[mi] * K + k0 + kq)
                             : zero8;
#pragma unroll
        for (int ni = 0; ni < 2; ++ni) {
            int nn = n0 + ni * 16 + l16;
            bfm[ni] = *(const short8*)(Bt + (size_t)nn * K + k0 + kq);
        }
#pragma unroll
        for (int mi = 0; mi < 2; ++mi)
#pragma unroll
            for (int ni = 0; ni < 2; ++ni)
                acc[mi][ni] = __builtin_amdgcn_mfma_f32_16x16x32_bf16(
                    af[mi], bfm[ni], acc[mi][ni], 0, 0, 0);
    }

#pragma unroll
    for (int ni = 0; ni < 2; ++ni) {
        int nn = n0 + ni * 16 + l16;
        float bv = bias ? bias[nn] : 0.f;
#pragma unroll
        for (int mi = 0; mi < 2; ++mi) {
#pragma unroll
            for (int r = 0; r < 4; ++r) {
                int m = m0 + mi * 16 + quad * 4 + r;
                if (m < M) {
                    float v = acc[mi][ni][r] + bv;
                    if (relu) v = fmaxf(v, 0.f);
                    size_t off = (size_t)m * N + nn;
                    if (out_f32) ((float*)C)[off] = v;
                    else         ((bf16*)C)[off] = __float2bfloat16(v);
                }
            }
        }
    }
}

// ---------------- CSR aggregation (one wave per node), bf16 acts, fp32 bias ----------------

template <int F>
__global__ void k_agg(const bf16* __restrict__ xw, const int* __restrict__ csr_ptr,
                      const int* __restrict__ csr_src, const float* __restrict__ dis,
                      const float* __restrict__ bias, bf16* __restrict__ out,
                      int n_nodes) {
    int gw = (int)((blockIdx.x * (size_t)blockDim.x + threadIdx.x) >> 6);
    int lane = threadIdx.x & 63;
    if (gw >= n_nodes) return;
    int nd = gw;
    int beg = csr_ptr[nd], end = csr_ptr[nd + 1];
    float dn = dis[nd];
    if (F == 128) {
        const __hip_bfloat162* xv = (const __hip_bfloat162*)xw;
        float ax = 0.f, ay = 0.f;
        for (int j = beg; j < end; ++j) {
            int s = csr_src[j];
            float wgt = dis[s] * dn;
            __hip_bfloat162 v = xv[(size_t)s * 64 + lane];
            ax += __bfloat162float(v.x) * wgt;
            ay += __bfloat162float(v.y) * wgt;
        }
        __hip_bfloat162 vs = xv[(size_t)nd * 64 + lane];
        float wl = dn * dn;
        ax += __bfloat162float(vs.x) * wl;
        ay += __bfloat162float(vs.y) * wl;
        ax = fmaxf(ax + bias[lane * 2], 0.f);
        ay = fmaxf(ay + bias[lane * 2 + 1], 0.f);
        __hip_bfloat162 o;
        o.x = __float2bfloat16(ax);
        o.y = __float2bfloat16(ay);
        ((__hip_bfloat162*)out)[(size_t)nd * 64 + lane] = o;
    } else {  // F == 64
        float acc = 0.f;
        for (int j = beg; j < end; ++j) {
            int s = csr_src[j];
            acc += __bfloat162float(xw[(size_t)s * 64 + lane]) * (dis[s] * dn);
        }
        acc += __bfloat162float(xw[(size_t)nd * 64 + lane]) * dn * dn;
        acc = fmaxf(acc + bias[lane], 0.f);
        out[(size_t)nd * 64 + lane] = __float2bfloat16(acc);
    }
}

// ---------------- launch ----------------

extern "C" void kernel_launch(void* const* d_in, const int* in_sizes, int n_in,
                              void* d_out, int out_size, void* d_ws, size_t ws_size,
                              hipStream_t stream) {
    const float* x   = (const float*)d_in[0];
    const int*   ei  = (const int*)d_in[1];
    const float* W1  = (const float*)d_in[2];
    const float* b1  = (const float*)d_in[3];
    const float* W2  = (const float*)d_in[4];
    const float* b2  = (const float*)d_in[5];
    const float* Wd1 = (const float*)d_in[6];
    const float* bd1 = (const float*)d_in[7];
    const float* Wd2 = (const float*)d_in[8];
    const float* bd2 = (const float*)d_in[9];
    float* out = (float*)d_out;

    const int n = in_sizes[0] / N_FEAT;    // 50000
    const int E = in_sizes[1] / 2;         // 600000
    const int* row = ei;                   // edge_index[0] (source)
    const int* col = ei + E;               // edge_index[1] (target)

    // workspace carve (~42 MB; proven ws >= 54.4 MB from r2)
    char* wp = (char*)d_ws;
    bf16* xb  = (bf16*)wp;  wp += (size_t)n * 128 * 2;   // bf16(x); reused as h1
    bf16* xw1 = (bf16*)wp;  wp += (size_t)n * 128 * 2;   // gemm1 out; reused as h3
    bf16* xw2 = (bf16*)wp;  wp += (size_t)n * 64 * 2;    // gemm2 out
    bf16* h2  = (bf16*)wp;  wp += (size_t)n * 64 * 2;    // agg2 out
    bf16* h1  = xb;                                      // xb dead after gemm1
    bf16* h3  = xw1;                                     // xw1 dead after agg1
    bf16* W1t = (bf16*)wp;  wp += 128 * 128 * 2;
    bf16* W2t = (bf16*)wp;  wp += 128 * 64 * 2;
    bf16* Wd1t= (bf16*)wp;  wp += 64 * 128 * 2;
    bf16* Wd2t= (bf16*)wp;  wp += 128 * 128 * 2;
    float* dis   = (float*)wp;  wp += (size_t)n * 4;
    int* deg     = (int*)wp;    wp += (size_t)n * 4;
    int* csr_ptr = (int*)wp;    wp += (size_t)(n + 1) * 4;
    int* cursor  = (int*)wp;    wp += (size_t)n * 4;
    int* part    = (int*)wp;    wp += (size_t)n * 4;
    int* bsums   = (int*)wp;    wp += 64 * 4;
    int* csr_src = (int*)wp;    wp += (size_t)E * 4;

    // --- CSR build ---
    hipMemsetAsync(deg, 0, (size_t)n * sizeof(int), stream);
    {
        int blk = 256, grd = (E + blk - 1) / blk;
        int nb = (n + 1023) / 1024;
        k_deg<<<grd, blk, 0, stream>>>(col, E, deg, n);
        k_scan1<<<nb, 1024, 0, stream>>>(deg, part, bsums, n);
        k_scan2<<<1, 64, 0, stream>>>(bsums, nb);
        k_scan3<<<nb, 1024, 0, stream>>>(deg, part, bsums, csr_ptr, cursor, dis, n);
        k_fill<<<grd, blk, 0, stream>>>(row, col, E, cursor, csr_src, n);
    }

    // --- conversions: x -> bf16, weights -> bf16 transposed ---
    {
        int c4 = n * 128 / 4;
        k_cvt<<<(c4 + 255) / 256, 256, 0, stream>>>(x, xb, c4);
        k_tr4<<<dim3(64, 4), 256, 0, stream>>>(W1, W1t, W2, W2t, Wd1, Wd1t, Wd2, Wd2t);
    }

    int mg = (n + 63) / 64;
    dim3 blk(256);

    // layer 1: xw1 = xb @ W1 ; h1 = relu(agg(xw1) + b1)
    k_gemm_mfma<<<dim3(mg, 128 / 64), blk, 0, stream>>>(xb, W1t, nullptr, xw1, 0,
                                                        n, N_FEAT, HID, 0);
    k_agg<HID><<<(n + 3) / 4, 256, 0, stream>>>(xw1, csr_ptr, csr_src, dis, b1, h1, n);

    // layer 2: xw2 = h1 @ W2 ; h2 = relu(agg(xw2) + b2)
    k_gemm_mfma<<<dim3(mg, 64 / 64), blk, 0, stream>>>(h1, W2t, nullptr, xw2, 0,
                                                       n, HID, OUTD, 0);
    k_agg<OUTD><<<(n + 3) / 4, 256, 0, stream>>>(xw2, csr_ptr, csr_src, dis, b2, h2, n);

    // decoder: h3 = relu(h2 @ Wd1 + bd1) ; out(fp32) = h3 @ Wd2 + bd2
    k_gemm_mfma<<<dim3(mg, 128 / 64), blk, 0, stream>>>(h2, Wd1t, bd1, h3, 0,
                                                        n, OUTD, HID, 1);
    k_gemm_mfma<<<dim3(mg, 128 / 64), blk, 0, stream>>>(h3, Wd2t, bd2, d_out, 1,
                                                        n, HID, N_FEAT, 0);
}

// Round 7
// 282.141 us; speedup vs baseline: 2.1489x; 1.2284x over previous
//
#include <hip/hip_runtime.h>
#include <hip/hip_bf16.h>

// GraphAutoencoder: 2x GCNConv (128->128->64) + 2x Linear decoder (64->128->128)
// N=50000, E=600000. Round 7 (on passing r6, 346us):
//  - k_agg was latency-bound (1 gather in flight/wave). Now: 8B/lane gathers
//    (2 edges/iter for F=128, 4 for F=64), manual 2x unroll, and dis[s]
//    pre-scaling moved into the GEMM epilogue so agg needs no dis gathers:
//       h[n] = relu(dn * (sum_{s in N(n) u {n}} dis[s]*xw[s]) + b)
//  - GEMM1 reads fp32 x directly (in-register bf16 convert): k_cvt removed.
// Dtypes (settled r1..r6): floats fp32, edge_index int32, out fp32.

#define N_FEAT 128
#define HID    128
#define OUTD   64

typedef __hip_bfloat16 bf16;
typedef __attribute__((ext_vector_type(8))) short short8;   // 8 bf16 = 4 VGPRs
typedef __attribute__((ext_vector_type(4))) short short4v;  // 4 bf16 = 8 B
typedef __attribute__((ext_vector_type(4))) float f32x4;    // MFMA accumulator

__device__ __forceinline__ float bs2f(short s) {
    return __builtin_bit_cast(float, ((unsigned)(unsigned short)s) << 16);
}
__device__ __forceinline__ short f2bs(float f) {
    __hip_bfloat16 h = __float2bfloat16(f);
    return __builtin_bit_cast(short, h);
}

// ---------------- CSR build (edge_index int32) ----------------

__global__ void k_deg(const int* __restrict__ col, int E, int* __restrict__ deg,
                      int n) {
    int e = blockIdx.x * blockDim.x + threadIdx.x;
    if (e >= E) return;
    int c = col[e];
    if ((unsigned)c < (unsigned)n) atomicAdd(&deg[c], 1);
}

__global__ void k_scan1(const int* __restrict__ deg, int* __restrict__ part,
                        int* __restrict__ bsums, int n) {
    __shared__ int s[1024];
    int t = threadIdx.x;
    int i = blockIdx.x * 1024 + t;
    int v = (i < n) ? deg[i] : 0;
    s[t] = v;
    __syncthreads();
    for (int off = 1; off < 1024; off <<= 1) {
        int u = (t >= off) ? s[t - off] : 0;
        __syncthreads();
        s[t] += u;
        __syncthreads();
    }
    if (i < n) part[i] = s[t] - v;
    if (t == 1023) bsums[blockIdx.x] = s[t];
}

__global__ void k_scan2(int* __restrict__ bsums, int nb) {
    __shared__ int s[64];
    int t = threadIdx.x;
    int v = (t < nb) ? bsums[t] : 0;
    s[t] = v;
    __syncthreads();
    for (int off = 1; off < 64; off <<= 1) {
        int u = (t >= off) ? s[t - off] : 0;
        __syncthreads();
        s[t] += u;
        __syncthreads();
    }
    if (t < nb) bsums[t] = s[t] - v;
}

__global__ void k_scan3(const int* __restrict__ deg, const int* __restrict__ part,
                        const int* __restrict__ bsums, int* __restrict__ csr_ptr,
                        int* __restrict__ cursor, float* __restrict__ dis, int n) {
    int i = blockIdx.x * 1024 + threadIdx.x;
    if (i >= n) return;
    int d = deg[i];
    int p = part[i] + bsums[blockIdx.x];
    csr_ptr[i] = p;
    cursor[i] = p;
    dis[i] = rsqrtf((float)(d + 1));
    if (i == n - 1) csr_ptr[n] = p + d;
}

__global__ void k_fill(const int* __restrict__ row, const int* __restrict__ col,
                       int E, int* __restrict__ cursor,
                       int* __restrict__ csr_src, int n) {
    int e = blockIdx.x * blockDim.x + threadIdx.x;
    if (e >= E) return;
    int r = row[e];
    int c = col[e];
    if ((unsigned)c >= (unsigned)n || (unsigned)r >= (unsigned)n) return;
    int pos = atomicAdd(&cursor[c], 1);
    csr_src[pos] = r;
}

// ---------------- weight transpose + fp32->bf16: Wt[n*K+k] = bf16(W[k*N+n]) ----------------

__global__ void k_tr4(const float* __restrict__ Wa, bf16* __restrict__ Ta,
                      const float* __restrict__ Wb, bf16* __restrict__ Tb,
                      const float* __restrict__ Wc, bf16* __restrict__ Tc,
                      const float* __restrict__ Wd, bf16* __restrict__ Td) {
    int which = blockIdx.y;
    const float* W; bf16* T; int K, N;
    if (which == 0)      { W = Wa; T = Ta; K = 128; N = 128; }
    else if (which == 1) { W = Wb; T = Tb; K = 128; N = 64;  }
    else if (which == 2) { W = Wc; T = Tc; K = 64;  N = 128; }
    else                 { W = Wd; T = Td; K = 128; N = 128; }
    int i = blockIdx.x * 256 + threadIdx.x;
    if (i >= K * N) return;
    int k = i / N, nn = i - k * N;
    T[nn * K + k] = __float2bfloat16(W[i]);
}

// ---------------- MFMA GEMM: C[M,N] = A[M,K] @ Wt[N,K]^T (+bias)(+relu)(*rowscale) ----------
// LDS-free: block 256 = 4 waves; block tile 64x64; wave tile 32x32 (2x2 of 16x16).
// A-frag: lane holds A[m=l16][k0+quad*8+j]; B-frag from Bt likewise; D: col=l16,row=quad*4+r.
// AF32: A is fp32 (converted in-register). OF32: C stored fp32 (d_out) else bf16.

template <int AF32, int OF32>
__global__ void k_gemm_mfma(const void* __restrict__ Av, const bf16* __restrict__ Bt,
                            const float* __restrict__ bias,
                            const float* __restrict__ rowscale,
                            void* __restrict__ C,
                            int M, int K, int N, int relu) {
    int t = threadIdx.x;
    int lane = t & 63, w = t >> 6;
    int quad = lane >> 4, l16 = lane & 15;
    int m0 = blockIdx.x * 64 + (w & 1) * 32;
    int n0 = blockIdx.y * 64 + (w >> 1) * 32;
    int kq = quad * 8;

    short8 zero8 = {0, 0, 0, 0, 0, 0, 0, 0};
    f32x4 acc[2][2];
#pragma unroll
    for (int mi = 0; mi < 2; ++mi)
#pragma unroll
        for (int ni = 0; ni < 2; ++ni)
#pragma unroll
            for (int r = 0; r < 4; ++r) acc[mi][ni][r] = 0.f;

    int mrow[2];
    bool mok[2];
#pragma unroll
    for (int mi = 0; mi < 2; ++mi) {
        mrow[mi] = m0 + mi * 16 + l16;
        mok[mi] = mrow[mi] < M;
    }

    for (int k0 = 0; k0 < K; k0 += 32) {
        short8 af[2], bfm[2];
#pragma unroll
        for (int mi = 0; mi < 2; ++mi) {
            if (AF32) {
                if (mok[mi]) {
                    const float* Af = (const float*)Av + (size_t)mrow[mi] * K + k0 + kq;
                    float4 a = *(const float4*)Af;
                    float4 b = *(const float4*)(Af + 4);
                    short8 r = {f2bs(a.x), f2bs(a.y), f2bs(a.z), f2bs(a.w),
                                f2bs(b.x), f2bs(b.y), f2bs(b.z), f2bs(b.w)};
                    af[mi] = r;
                } else af[mi] = zero8;
            } else {
                af[mi] = mok[mi]
                    ? *(const short8*)((const bf16*)Av + (size_t)mrow[mi] * K + k0 + kq)
                    : zero8;
            }
        }
#pragma unroll
        for (int ni = 0; ni < 2; ++ni) {
            int nn = n0 + ni * 16 + l16;
            bfm[ni] = *(const short8*)(Bt + (size_t)nn * K + k0 + kq);
        }
#pragma unroll
        for (int mi = 0; mi < 2; ++mi)
#pragma unroll
            for (int ni = 0; ni < 2; ++ni)
                acc[mi][ni] = __builtin_amdgcn_mfma_f32_16x16x32_bf16(
                    af[mi], bfm[ni], acc[mi][ni], 0, 0, 0);
    }

#pragma unroll
    for (int ni = 0; ni < 2; ++ni) {
        int nn = n0 + ni * 16 + l16;
        float bv = bias ? bias[nn] : 0.f;
#pragma unroll
        for (int mi = 0; mi < 2; ++mi) {
#pragma unroll
            for (int r = 0; r < 4; ++r) {
                int m = m0 + mi * 16 + quad * 4 + r;
                if (m < M) {
                    float v = acc[mi][ni][r] + bv;
                    if (relu) v = fmaxf(v, 0.f);
                    if (rowscale) v *= rowscale[m];
                    size_t off = (size_t)m * N + nn;
                    if (OF32) ((float*)C)[off] = v;
                    else      ((bf16*)C)[off] = f2bs(v) , ((short*)C)[off] = f2bs(v);
                }
            }
        }
    }
}

// ---------------- CSR aggregation: h[n] = relu(dn * sum(xws[s], s in N u {n}) + b) ----------
// xws rows are pre-scaled by dis[row] (GEMM epilogue). 8B/lane gathers:
// F=128 -> 32 lanes/row, 2 edges per wave-iter; F=64 -> 16 lanes/row, 4 edges.
// Manual 2x unroll => 4 (resp. 8) gathers in flight per wave.

template <int F>
__global__ void k_agg(const bf16* __restrict__ xw, const int* __restrict__ csr_ptr,
                      const int* __restrict__ csr_src, const float* __restrict__ dis,
                      const float* __restrict__ bias, bf16* __restrict__ out,
                      int n_nodes) {
    constexpr int LPG = F / 4;        // lanes per row-group (32 or 16)
    constexpr int GRP = 64 / LPG;     // edge groups per wave (2 or 4)
    int wv = (int)((blockIdx.x * (size_t)blockDim.x + threadIdx.x) >> 6);
    if (wv >= n_nodes) return;
    int lane = threadIdx.x & 63;
    int sub = lane / LPG, li = lane % LPG;
    int beg = csr_ptr[wv];
    int cnt = csr_ptr[wv + 1] - beg + 1;   // edges + self (self is index cnt-1)
    float dn = dis[wv];

    float a0 = 0.f, a1 = 0.f, a2 = 0.f, a3 = 0.f;

    int t = sub;
    // 2x unrolled: two gathers (per group) in flight
    for (; t + GRP < cnt; t += 2 * GRP) {
        int s0 = (t == cnt - 1) ? wv : csr_src[beg + t];
        int t1 = t + GRP;
        int s1 = (t1 == cnt - 1) ? wv : csr_src[beg + t1];
        short4v v0 = *((const short4v*)(xw + (size_t)s0 * F) + li);
        short4v v1 = *((const short4v*)(xw + (size_t)s1 * F) + li);
        a0 += bs2f(v0[0]) + bs2f(v1[0]);
        a1 += bs2f(v0[1]) + bs2f(v1[1]);
        a2 += bs2f(v0[2]) + bs2f(v1[2]);
        a3 += bs2f(v0[3]) + bs2f(v1[3]);
    }
    if (t < cnt) {
        int s = (t == cnt - 1) ? wv : csr_src[beg + t];
        short4v v = *((const short4v*)(xw + (size_t)s * F) + li);
        a0 += bs2f(v[0]); a1 += bs2f(v[1]); a2 += bs2f(v[2]); a3 += bs2f(v[3]);
    }

    // reduce across groups (lanes sub>0 fold into sub==0)
#pragma unroll
    for (int d = 32; d >= LPG; d >>= 1) {
        a0 += __shfl_down(a0, d);
        a1 += __shfl_down(a1, d);
        a2 += __shfl_down(a2, d);
        a3 += __shfl_down(a3, d);
    }

    if (lane < LPG) {
        float4 b4 = *(const float4*)(bias + lane * 4);
        short4v o;
        o[0] = f2bs(fmaxf(dn * a0 + b4.x, 0.f));
        o[1] = f2bs(fmaxf(dn * a1 + b4.y, 0.f));
        o[2] = f2bs(fmaxf(dn * a2 + b4.z, 0.f));
        o[3] = f2bs(fmaxf(dn * a3 + b4.w, 0.f));
        *((short4v*)(out + (size_t)wv * F) + lane) = o;
    }
}

// ---------------- launch ----------------

extern "C" void kernel_launch(void* const* d_in, const int* in_sizes, int n_in,
                              void* d_out, int out_size, void* d_ws, size_t ws_size,
                              hipStream_t stream) {
    const float* x   = (const float*)d_in[0];
    const int*   ei  = (const int*)d_in[1];
    const float* W1  = (const float*)d_in[2];
    const float* b1  = (const float*)d_in[3];
    const float* W2  = (const float*)d_in[4];
    const float* b2  = (const float*)d_in[5];
    const float* Wd1 = (const float*)d_in[6];
    const float* bd1 = (const float*)d_in[7];
    const float* Wd2 = (const float*)d_in[8];
    const float* bd2 = (const float*)d_in[9];

    const int n = in_sizes[0] / N_FEAT;    // 50000
    const int E = in_sizes[1] / 2;         // 600000
    const int* row = ei;                   // edge_index[0] (source)
    const int* col = ei + E;               // edge_index[1] (target)

    // workspace carve (~29 MB)
    char* wp = (char*)d_ws;
    bf16* xw1 = (bf16*)wp;  wp += (size_t)n * 128 * 2;   // gemm1 out (pre-scaled); reused as h3
    bf16* h1  = (bf16*)wp;  wp += (size_t)n * 128 * 2;   // agg1 out
    bf16* xw2 = (bf16*)wp;  wp += (size_t)n * 64 * 2;    // gemm2 out (pre-scaled)
    bf16* h2  = (bf16*)wp;  wp += (size_t)n * 64 * 2;    // agg2 out
    bf16* h3  = xw1;                                     // xw1 dead after agg1
    bf16* W1t = (bf16*)wp;  wp += 128 * 128 * 2;
    bf16* W2t = (bf16*)wp;  wp += 128 * 64 * 2;
    bf16* Wd1t= (bf16*)wp;  wp += 64 * 128 * 2;
    bf16* Wd2t= (bf16*)wp;  wp += 128 * 128 * 2;
    float* dis   = (float*)wp;  wp += (size_t)n * 4;
    int* deg     = (int*)wp;    wp += (size_t)n * 4;
    int* csr_ptr = (int*)wp;    wp += (size_t)(n + 1) * 4;
    int* cursor  = (int*)wp;    wp += (size_t)n * 4;
    int* part    = (int*)wp;    wp += (size_t)n * 4;
    int* bsums   = (int*)wp;    wp += 64 * 4;
    int* csr_src = (int*)wp;    wp += (size_t)E * 4;

    // --- CSR build ---
    hipMemsetAsync(deg, 0, (size_t)n * sizeof(int), stream);
    {
        int blk = 256, grd = (E + blk - 1) / blk;
        int nb = (n + 1023) / 1024;
        k_deg<<<grd, blk, 0, stream>>>(col, E, deg, n);
        k_scan1<<<nb, 1024, 0, stream>>>(deg, part, bsums, n);
        k_scan2<<<1, 64, 0, stream>>>(bsums, nb);
        k_scan3<<<nb, 1024, 0, stream>>>(deg, part, bsums, csr_ptr, cursor, dis, n);
        k_fill<<<grd, blk, 0, stream>>>(row, col, E, cursor, csr_src, n);
    }

    // --- weight transposes (fp32 -> bf16) ---
    k_tr4<<<dim3(64, 4), 256, 0, stream>>>(W1, W1t, W2, W2t, Wd1, Wd1t, Wd2, Wd2t);

    int mg = (n + 63) / 64;
    dim3 blk(256);
    int aggb = (n + 3) / 4;

    // layer 1: xw1 = dis .* (x @ W1) ; h1 = relu(dn*agg(xw1) + b1)
    k_gemm_mfma<1, 0><<<dim3(mg, 128 / 64), blk, 0, stream>>>(
        x, W1t, nullptr, dis, xw1, n, N_FEAT, HID, 0);
    k_agg<HID><<<aggb, 256, 0, stream>>>(xw1, csr_ptr, csr_src, dis, b1, h1, n);

    // layer 2: xw2 = dis .* (h1 @ W2) ; h2 = relu(dn*agg(xw2) + b2)
    k_gemm_mfma<0, 0><<<dim3(mg, 64 / 64), blk, 0, stream>>>(
        h1, W2t, nullptr, dis, xw2, n, HID, OUTD, 0);
    k_agg<OUTD><<<aggb, 256, 0, stream>>>(xw2, csr_ptr, csr_src, dis, b2, h2, n);

    // decoder: h3 = relu(h2 @ Wd1 + bd1) ; out(fp32) = h3 @ Wd2 + bd2
    k_gemm_mfma<0, 0><<<dim3(mg, 128 / 64), blk, 0, stream>>>(
        h2, Wd1t, bd1, nullptr, h3, n, OUTD, HID, 1);
    k_gemm_mfma<0, 1><<<dim3(mg, 128 / 64), blk, 0, stream>>>(
        h3, Wd2t, bd2, nullptr, d_out, n, HID, N_FEAT, 0);
}